// Round 3
// baseline (251.390 us; speedup 1.0000x reference)
//
#include <hip/hip_runtime.h>

#define B_    8
#define CIN   128
#define COUT  128
#define NX    8192
#define KMJ   32
#define MODES 256

typedef short bf16x8 __attribute__((ext_vector_type(8)));
typedef float f32x4  __attribute__((ext_vector_type(4)));

__device__ __forceinline__ float bf2f(unsigned short u) {
    union { unsigned int i; float f; } v; v.i = ((unsigned int)u) << 16; return v.f;
}
__device__ __forceinline__ unsigned short f2bf(float f) {
    union { float f; unsigned int i; } v; v.f = f;
    unsigned int x = v.i;
    return (unsigned short)((x + 0x7fffu + ((x >> 16) & 1u)) >> 16);
}
// 8 consecutive fp32 -> bf16x8 (RNE)
__device__ __forceinline__ bf16x8 cvt8(const float* __restrict__ p) {
    f32x4 a = *(const f32x4*)p;
    f32x4 b = *(const f32x4*)(p + 4);
    bf16x8 r;
    r[0] = (short)f2bf(a[0]); r[1] = (short)f2bf(a[1]);
    r[2] = (short)f2bf(a[2]); r[3] = (short)f2bf(a[3]);
    r[4] = (short)f2bf(b[0]); r[5] = (short)f2bf(b[1]);
    r[6] = (short)f2bf(b[2]); r[7] = (short)f2bf(b[3]);
    return r;
}

// ---------------------------------------------------------------------------
// K1: Wk[k][i*COUT+o] = sum_j weights[(i*COUT+o)*KMJ + j] * D[j*MODES + k]
// MFMA GEMM: M=16384 (io), Kdim=32 (j, one MFMA step), N=256 (k). fp32 in,
// bf16 frags, bf16 Wk out (workspace).
// ---------------------------------------------------------------------------
__global__ __launch_bounds__(256) void k1_wk(const float* __restrict__ W,
                                             const float* __restrict__ D,
                                             unsigned short* __restrict__ Wk) {
    int wave = threadIdx.x >> 6;
    int lane = threadIdx.x & 63;
    int gw   = blockIdx.x * 4 + wave;   // 0..1023
    int kt   = gw & 15;                 // 16 k-tiles of 16 modes
    int ioch = gw >> 4;                 // 64 chunks of 256 io
    int k0   = kt * 16;
    int quad = lane >> 4, l16 = lane & 15;

    // B-frag: B[j = quad*8+jj][n = k0+l16] = D[j][k0+l16]
    bf16x8 bfrag;
#pragma unroll
    for (int jj = 0; jj < 8; jj++)
        bfrag[jj] = (short)f2bf(D[(quad * 8 + jj) * MODES + k0 + l16]);

    int io0 = ioch * 256;
#pragma unroll 4
    for (int t = 0; t < 16; t++) {
        int io = io0 + t * 16 + l16;
        bf16x8 afrag = cvt8(W + (size_t)io * KMJ + quad * 8);
        f32x4 acc = {0.f, 0.f, 0.f, 0.f};
        acc = __builtin_amdgcn_mfma_f32_16x16x32_bf16(afrag, bfrag, acc, 0, 0, 0);
        // C/D: col (k) = l16, rows (io) = quad*4 + r
        int iorow = io0 + t * 16 + quad * 4;
        ushort4 st;
        st.x = f2bf(acc[0]); st.y = f2bf(acc[1]);
        st.z = f2bf(acc[2]); st.w = f2bf(acc[3]);
        *(ushort4*)(Wk + (size_t)(k0 + l16) * (CIN * COUT) + iorow) = st;
    }
}

// ---------------------------------------------------------------------------
// K2: x_hat[b][c][k] += sum_{n in chunk} x[b][c][n] * wb[b][n][k]
// Split-K GEMM, per-block tile 128c x 256k, R-chunk = 256 (8 steps of 32).
// grid (32 rsplit, 8 b), 512 threads = 8 waves (2m x 4n of 64x64 wave tiles).
// fp32 loads converted to bf16 frags in registers; fp32 atomicAdd epilogue.
// ---------------------------------------------------------------------------
__global__ __launch_bounds__(512) void k2_xhat(const float* __restrict__ X,
                                               const float* __restrict__ WB,
                                               float* __restrict__ XH) {
    int b = blockIdx.y;
    int r0 = blockIdx.x * 256;
    int wave = threadIdx.x >> 6;
    int lane = threadIdx.x & 63;
    int wm = wave >> 2;       // 0..1
    int wn = wave & 3;        // 0..3
    int quad = lane >> 4, l16 = lane & 15;

    const float* xb  = X  + (size_t)b * CIN * NX;
    const float* wbb = WB + (size_t)b * NX * MODES;

    f32x4 acc[4][4];
#pragma unroll
    for (int i = 0; i < 4; i++)
#pragma unroll
        for (int j = 0; j < 4; j++) acc[i][j] = (f32x4){0.f, 0.f, 0.f, 0.f};

    for (int step = 0; step < 8; step++) {
        int rs = r0 + step * 32;
        bf16x8 af[4];
#pragma unroll
        for (int tm = 0; tm < 4; tm++) {
            int c = wm * 64 + tm * 16 + l16;
            af[tm] = cvt8(xb + (size_t)c * NX + rs + quad * 8);
        }
        bf16x8 bfv[4];
#pragma unroll
        for (int tn = 0; tn < 4; tn++) {
            int km = wn * 64 + tn * 16 + l16;
            const float* p = wbb + (size_t)(rs + quad * 8) * MODES + km;
#pragma unroll
            for (int jj = 0; jj < 8; jj++) bfv[tn][jj] = (short)f2bf(p[jj * MODES]);
        }
#pragma unroll
        for (int tm = 0; tm < 4; tm++)
#pragma unroll
            for (int tn = 0; tn < 4; tn++)
                acc[tm][tn] = __builtin_amdgcn_mfma_f32_16x16x32_bf16(af[tm], bfv[tn], acc[tm][tn], 0, 0, 0);
    }

    float* xhb = XH + (size_t)b * CIN * MODES;
#pragma unroll
    for (int tm = 0; tm < 4; tm++) {
        int c = wm * 64 + tm * 16 + quad * 4;
#pragma unroll
        for (int tn = 0; tn < 4; tn++) {
            int km = wn * 64 + tn * 16 + l16;
#pragma unroll
            for (int r = 0; r < 4; r++)
                atomicAdd(xhb + (size_t)(c + r) * MODES + km, acc[tm][tn][r]);
        }
    }
}

// ---------------------------------------------------------------------------
// K3: y_hat[b][o][k] = sum_i x_hat[b][i][k] * Wk[k][i*COUT+o]
// grid (32 k-tiles of 8, 8 b), 256 threads. x_hat slice staged to LDS.
// ---------------------------------------------------------------------------
__global__ __launch_bounds__(256) void k3_yhat(const float* __restrict__ XH,
                                               const unsigned short* __restrict__ Wk,
                                               unsigned short* __restrict__ YH) {
    __shared__ float xs[8][128];
    __shared__ float ys[8][128];
    int b  = blockIdx.y;
    int k0 = blockIdx.x * 8;
    int t  = threadIdx.x;
    const float* xhb = XH + (size_t)b * CIN * MODES;
#pragma unroll
    for (int l = 0; l < 4; l++) {
        int e = l * 256 + t;          // 0..1023
        int kk = e & 7, i = e >> 3;
        xs[kk][i] = xhb[(size_t)i * MODES + k0 + kk];
    }
    __syncthreads();
    int o = t & 127, kh = t >> 7;
#pragma unroll
    for (int p = 0; p < 4; p++) {
        int kk = p * 2 + kh;
        int k  = k0 + kk;
        const unsigned short* wp = Wk + (size_t)k * (CIN * COUT) + o;
        float acc = 0.f;
#pragma unroll 8
        for (int i = 0; i < 128; i++)
            acc += xs[kk][i] * bf2f(wp[i * COUT]);
        ys[kk][o] = acc;
    }
    __syncthreads();
    unsigned short* yb = YH + (size_t)b * COUT * MODES;
#pragma unroll
    for (int l = 0; l < 4; l++) {
        int e = l * 256 + t;
        int kk = e & 7, oo = e >> 3;
        yb[(size_t)oo * MODES + k0 + kk] = f2bf(ys[kk][oo]);
    }
}

// ---------------------------------------------------------------------------
// K4: y[b][c][n] = sum_k y_hat[b][c][k] * bases[b][n][k]
// NT GEMM per b: M=128, N=8192, K=256. 128x128 tile, 4 waves, synchronous
// register-mediated LDS staging. bases fp32 -> bf16 on the fly; y out fp32.
// ---------------------------------------------------------------------------
__global__ __launch_bounds__(256) void k4_y(const unsigned short* __restrict__ YH,
                                            const float* __restrict__ BA,
                                            float* __restrict__ Y) {
    __shared__ __align__(16) unsigned short As[128 * 32];
    __shared__ __align__(16) unsigned short Bs[128 * 32];
    int b  = blockIdx.y;
    int n0 = blockIdx.x * 128;
    int t  = threadIdx.x;
    int wave = t >> 6, lane = t & 63;
    int wm = wave >> 1, wn = wave & 1;
    int quad = lane >> 4, l16 = lane & 15;

    const unsigned short* yhb = YH + (size_t)b * COUT * MODES;
    const float* bab = BA + (size_t)b * NX * MODES + (size_t)n0 * MODES;

    f32x4 acc[4][4];
#pragma unroll
    for (int i = 0; i < 4; i++)
#pragma unroll
        for (int j = 0; j < 4; j++) acc[i][j] = (f32x4){0.f, 0.f, 0.f, 0.f};

    for (int step = 0; step < 8; step++) {
        int ks = step * 32;
        // 256 threads x 8 elems x 2 chunks = 4096 elems per 128x32 tile.
#pragma unroll
        for (int p = 0; p < 2; p++) {
            int E = p * 2048 + t * 8;      // element index (row-major, no straddle)
            int row = E >> 5, kk = E & 31;
            bf16x8 av = *(const bf16x8*)(yhb + (size_t)row * MODES + ks + kk);
            bf16x8 bv = cvt8(bab + (size_t)row * MODES + ks + kk);
            *(bf16x8*)(As + E) = av;
            *(bf16x8*)(Bs + E) = bv;
        }
        __syncthreads();

        bf16x8 af[4], bfv[4];
#pragma unroll
        for (int tm = 0; tm < 4; tm++) {
            int c = wm * 64 + tm * 16 + l16;
            af[tm] = *(const bf16x8*)(As + c * 32 + quad * 8);
        }
#pragma unroll
        for (int tn = 0; tn < 4; tn++) {
            int n = wn * 64 + tn * 16 + l16;
            bfv[tn] = *(const bf16x8*)(Bs + n * 32 + quad * 8);
        }
#pragma unroll
        for (int tm = 0; tm < 4; tm++)
#pragma unroll
            for (int tn = 0; tn < 4; tn++)
                acc[tm][tn] = __builtin_amdgcn_mfma_f32_16x16x32_bf16(af[tm], bfv[tn], acc[tm][tn], 0, 0, 0);
        __syncthreads();
    }

    float* yb = Y + (size_t)b * COUT * NX;
#pragma unroll
    for (int tm = 0; tm < 4; tm++) {
        int o = wm * 64 + tm * 16 + quad * 4;
#pragma unroll
        for (int tn = 0; tn < 4; tn++) {
            int n = n0 + wn * 64 + tn * 16 + l16;
#pragma unroll
            for (int r = 0; r < 4; r++)
                yb[(size_t)(o + r) * NX + n] = acc[tm][tn][r];
        }
    }
}

extern "C" void kernel_launch(void* const* d_in, const int* in_sizes, int n_in,
                              void* d_out, int out_size, void* d_ws, size_t ws_size,
                              hipStream_t stream) {
    const float* X  = (const float*)d_in[0];  // [8][128][8192] fp32
    const float* WB = (const float*)d_in[1];  // [8][8192][256] fp32
    const float* BA = (const float*)d_in[2];  // [8][8192][256] fp32
    const float* W  = (const float*)d_in[3];  // [128][128][32] fp32
    const float* D  = (const float*)d_in[4];  // [32][256]      fp32
    float* Y = (float*)d_out;                 // [8][128][8192] fp32

    char* ws = (char*)d_ws;
    float*          XH = (float*)ws;                                  // 1 MB fp32
    unsigned short* Wk = (unsigned short*)(ws + (1u << 20));          // 8 MB bf16
    unsigned short* YH = (unsigned short*)(ws + (1u << 20) + (size_t)CIN * COUT * MODES * 2); // 0.5 MB

    hipMemsetAsync(XH, 0, (size_t)B_ * CIN * MODES * sizeof(float), stream);

    k1_wk  <<<256,        256, 0, stream>>>(W, D, Wk);
    k2_xhat<<<dim3(32, 8), 512, 0, stream>>>(X, WB, XH);
    k3_yhat<<<dim3(32, 8), 256, 0, stream>>>(XH, Wk, YH);
    k4_y   <<<dim3(64, 8), 256, 0, stream>>>(YH, BA, Y);
}

// Round 4
// 251.124 us; speedup vs baseline: 1.0011x; 1.0011x over previous
//
#include <hip/hip_runtime.h>

#define B_    8
#define CIN   128
#define COUT  128
#define NX    8192
#define KMJ   32
#define MODES 256

typedef short bf16x8 __attribute__((ext_vector_type(8)));
typedef float f32x4  __attribute__((ext_vector_type(4)));

__device__ __forceinline__ float bf2f(unsigned short u) {
    union { unsigned int i; float f; } v; v.i = ((unsigned int)u) << 16; return v.f;
}
__device__ __forceinline__ unsigned short f2bf(float f) {
    union { float f; unsigned int i; } v; v.f = f;
    unsigned int x = v.i;
    return (unsigned short)((x + 0x7fffu + ((x >> 16) & 1u)) >> 16);
}
// 8 consecutive fp32 -> bf16x8 (RNE)
__device__ __forceinline__ bf16x8 cvt8(const float* __restrict__ p) {
    f32x4 a = *(const f32x4*)p;
    f32x4 b = *(const f32x4*)(p + 4);
    bf16x8 r;
    r[0] = (short)f2bf(a[0]); r[1] = (short)f2bf(a[1]);
    r[2] = (short)f2bf(a[2]); r[3] = (short)f2bf(a[3]);
    r[4] = (short)f2bf(b[0]); r[5] = (short)f2bf(b[1]);
    r[6] = (short)f2bf(b[2]); r[7] = (short)f2bf(b[3]);
    return r;
}
__device__ __forceinline__ ushort4 cvt4(f32x4 a) {
    ushort4 r;
    r.x = f2bf(a[0]); r.y = f2bf(a[1]); r.z = f2bf(a[2]); r.w = f2bf(a[3]);
    return r;
}

// ---------------------------------------------------------------------------
// K1: Wk[k][i*COUT+o] = sum_j weights[(i*COUT+o)*KMJ + j] * D[j*MODES + k]
// ---------------------------------------------------------------------------
__global__ __launch_bounds__(256) void k1_wk(const float* __restrict__ W,
                                             const float* __restrict__ D,
                                             unsigned short* __restrict__ Wk) {
    int wave = threadIdx.x >> 6;
    int lane = threadIdx.x & 63;
    int gw   = blockIdx.x * 4 + wave;   // 0..1023
    int kt   = gw & 15;
    int ioch = gw >> 4;
    int k0   = kt * 16;
    int quad = lane >> 4, l16 = lane & 15;

    bf16x8 bfrag;
#pragma unroll
    for (int jj = 0; jj < 8; jj++)
        bfrag[jj] = (short)f2bf(D[(quad * 8 + jj) * MODES + k0 + l16]);

    int io0 = ioch * 256;
#pragma unroll 4
    for (int t = 0; t < 16; t++) {
        int io = io0 + t * 16 + l16;
        bf16x8 afrag = cvt8(W + (size_t)io * KMJ + quad * 8);
        f32x4 acc = {0.f, 0.f, 0.f, 0.f};
        acc = __builtin_amdgcn_mfma_f32_16x16x32_bf16(afrag, bfrag, acc, 0, 0, 0);
        int iorow = io0 + t * 16 + quad * 4;
        ushort4 st;
        st.x = f2bf(acc[0]); st.y = f2bf(acc[1]);
        st.z = f2bf(acc[2]); st.w = f2bf(acc[3]);
        *(ushort4*)(Wk + (size_t)(k0 + l16) * (CIN * COUT) + iorow) = st;
    }
}

// ---------------------------------------------------------------------------
// K2 v2: x_hat[b][c][kt*128+km] += sum_n x[b][c][n]*wb[b][n][kt*128+km]
// LDS-staged MFMA GEMM. grid (32 n-chunks, 2 k-halves, 8 b) = 512 blocks,
// 256 threads (4 waves, 2x2 -> 64x64 wave tiles). 8 K-steps of 32 n.
// Staging: coalesced f32x4 -> cvt -> LDS bf16. A-frags ds_read_b128 (pad 40,
// 2-way free); B-frags 8x ds_read_u16 from direct [n][k] layout (pad 140,
// ~4-way, 1.58x — irrelevant vs BW budget). fp32 atomic epilogue.
// ---------------------------------------------------------------------------
__global__ __launch_bounds__(256) void k2_xhat(const float* __restrict__ X,
                                               const float* __restrict__ WB,
                                               float* __restrict__ XH) {
    __shared__ __align__(16) unsigned short Xs[128 * 40];    // [c][40], use [0..31]
    __shared__ __align__(16) unsigned short WBs[32 * 140];   // [n][140], use [0..127]
    int nt = blockIdx.x;           // 0..31  (n-chunk of 256)
    int kt = blockIdx.y;           // 0..1   (mode-half of 128)
    int b  = blockIdx.z;
    int r0 = nt * 256;
    int t  = threadIdx.x;
    int wave = t >> 6, lane = t & 63;
    int wm = wave >> 1, wn = wave & 1;
    int quad = lane >> 4, l16 = lane & 15;

    const float* xb  = X  + (size_t)b * CIN * NX;
    const float* wbb = WB + (size_t)b * NX * MODES + kt * 128;

    // staging maps
    int xn4 = t & 7,  xc0 = t >> 3;   // X: 8 f32x4 per 32-n row; 32 c-rows/round
    int wm4 = t & 31, wn0 = t >> 5;   // WB: 32 f32x4 per 128-k row; 8 n-rows/round

    f32x4 acc[4][4];
#pragma unroll
    for (int i = 0; i < 4; i++)
#pragma unroll
        for (int j = 0; j < 4; j++) acc[i][j] = (f32x4){0.f, 0.f, 0.f, 0.f};

    for (int s = 0; s < 8; s++) {
        int rs = r0 + s * 32;
        f32x4 xv[4], wv[4];
#pragma unroll
        for (int r = 0; r < 4; r++)
            xv[r] = *(const f32x4*)(xb + (size_t)(xc0 + 32 * r) * NX + rs + xn4 * 4);
#pragma unroll
        for (int r = 0; r < 4; r++)
            wv[r] = *(const f32x4*)(wbb + (size_t)(rs + wn0 + 8 * r) * MODES + wm4 * 4);

        __syncthreads();   // previous step's frag reads complete
#pragma unroll
        for (int r = 0; r < 4; r++)
            *(ushort4*)(Xs + (xc0 + 32 * r) * 40 + xn4 * 4) = cvt4(xv[r]);
#pragma unroll
        for (int r = 0; r < 4; r++)
            *(ushort4*)(WBs + (wn0 + 8 * r) * 140 + wm4 * 4) = cvt4(wv[r]);
        __syncthreads();   // staging visible

        bf16x8 af[4];
#pragma unroll
        for (int tm = 0; tm < 4; tm++) {
            int c = wm * 64 + tm * 16 + l16;
            af[tm] = *(const bf16x8*)(Xs + c * 40 + quad * 8);
        }
        bf16x8 bfv[4];
#pragma unroll
        for (int tn = 0; tn < 4; tn++) {
            int km = wn * 64 + tn * 16 + l16;
#pragma unroll
            for (int jj = 0; jj < 8; jj++)
                bfv[tn][jj] = (short)WBs[(quad * 8 + jj) * 140 + km];
        }
#pragma unroll
        for (int tm = 0; tm < 4; tm++)
#pragma unroll
            for (int tn = 0; tn < 4; tn++)
                acc[tm][tn] = __builtin_amdgcn_mfma_f32_16x16x32_bf16(af[tm], bfv[tn], acc[tm][tn], 0, 0, 0);
    }

    float* xhb = XH + (size_t)b * CIN * MODES + kt * 128;
#pragma unroll
    for (int tm = 0; tm < 4; tm++) {
        int c = wm * 64 + tm * 16 + quad * 4;
#pragma unroll
        for (int tn = 0; tn < 4; tn++) {
            int km = wn * 64 + tn * 16 + l16;
#pragma unroll
            for (int r = 0; r < 4; r++)
                atomicAdd(xhb + (size_t)(c + r) * MODES + km, acc[tm][tn][r]);
        }
    }
}

// ---------------------------------------------------------------------------
// K3: y_hat[b][o][k] = sum_i x_hat[b][i][k] * Wk[k][i*COUT+o]
// ---------------------------------------------------------------------------
__global__ __launch_bounds__(256) void k3_yhat(const float* __restrict__ XH,
                                               const unsigned short* __restrict__ Wk,
                                               unsigned short* __restrict__ YH) {
    __shared__ float xs[8][128];
    __shared__ float ys[8][128];
    int b  = blockIdx.y;
    int k0 = blockIdx.x * 8;
    int t  = threadIdx.x;
    const float* xhb = XH + (size_t)b * CIN * MODES;
#pragma unroll
    for (int l = 0; l < 4; l++) {
        int e = l * 256 + t;
        int kk = e & 7, i = e >> 3;
        xs[kk][i] = xhb[(size_t)i * MODES + k0 + kk];
    }
    __syncthreads();
    int o = t & 127, kh = t >> 7;
#pragma unroll
    for (int p = 0; p < 4; p++) {
        int kk = p * 2 + kh;
        int k  = k0 + kk;
        const unsigned short* wp = Wk + (size_t)k * (CIN * COUT) + o;
        float acc = 0.f;
#pragma unroll 8
        for (int i = 0; i < 128; i++)
            acc += xs[kk][i] * bf2f(wp[i * COUT]);
        ys[kk][o] = acc;
    }
    __syncthreads();
    unsigned short* yb = YH + (size_t)b * COUT * MODES;
#pragma unroll
    for (int l = 0; l < 4; l++) {
        int e = l * 256 + t;
        int kk = e & 7, oo = e >> 3;
        yb[(size_t)oo * MODES + k0 + kk] = f2bf(ys[kk][oo]);
    }
}

// ---------------------------------------------------------------------------
// K4: y[b][c][n] = sum_k y_hat[b][c][k] * bases[b][n][k]
// ---------------------------------------------------------------------------
__global__ __launch_bounds__(256) void k4_y(const unsigned short* __restrict__ YH,
                                            const float* __restrict__ BA,
                                            float* __restrict__ Y) {
    __shared__ __align__(16) unsigned short As[128 * 32];
    __shared__ __align__(16) unsigned short Bs[128 * 32];
    int b  = blockIdx.y;
    int n0 = blockIdx.x * 128;
    int t  = threadIdx.x;
    int wave = t >> 6, lane = t & 63;
    int wm = wave >> 1, wn = wave & 1;
    int quad = lane >> 4, l16 = lane & 15;

    const unsigned short* yhb = YH + (size_t)b * COUT * MODES;
    const float* bab = BA + (size_t)b * NX * MODES + (size_t)n0 * MODES;

    f32x4 acc[4][4];
#pragma unroll
    for (int i = 0; i < 4; i++)
#pragma unroll
        for (int j = 0; j < 4; j++) acc[i][j] = (f32x4){0.f, 0.f, 0.f, 0.f};

    for (int step = 0; step < 8; step++) {
        int ks = step * 32;
#pragma unroll
        for (int p = 0; p < 2; p++) {
            int E = p * 2048 + t * 8;
            int row = E >> 5, kk = E & 31;
            bf16x8 av = *(const bf16x8*)(yhb + (size_t)row * MODES + ks + kk);
            bf16x8 bv = cvt8(bab + (size_t)row * MODES + ks + kk);
            *(bf16x8*)(As + E) = av;
            *(bf16x8*)(Bs + E) = bv;
        }
        __syncthreads();

        bf16x8 af[4], bfv[4];
#pragma unroll
        for (int tm = 0; tm < 4; tm++) {
            int c = wm * 64 + tm * 16 + l16;
            af[tm] = *(const bf16x8*)(As + c * 32 + quad * 8);
        }
#pragma unroll
        for (int tn = 0; tn < 4; tn++) {
            int n = wn * 64 + tn * 16 + l16;
            bfv[tn] = *(const bf16x8*)(Bs + n * 32 + quad * 8);
        }
#pragma unroll
        for (int tm = 0; tm < 4; tm++)
#pragma unroll
            for (int tn = 0; tn < 4; tn++)
                acc[tm][tn] = __builtin_amdgcn_mfma_f32_16x16x32_bf16(af[tm], bfv[tn], acc[tm][tn], 0, 0, 0);
        __syncthreads();
    }

    float* yb = Y + (size_t)b * COUT * NX;
#pragma unroll
    for (int tm = 0; tm < 4; tm++) {
        int o = wm * 64 + tm * 16 + quad * 4;
#pragma unroll
        for (int tn = 0; tn < 4; tn++) {
            int n = n0 + wn * 64 + tn * 16 + l16;
#pragma unroll
            for (int r = 0; r < 4; r++)
                yb[(size_t)(o + r) * NX + n] = acc[tm][tn][r];
        }
    }
}

extern "C" void kernel_launch(void* const* d_in, const int* in_sizes, int n_in,
                              void* d_out, int out_size, void* d_ws, size_t ws_size,
                              hipStream_t stream) {
    const float* X  = (const float*)d_in[0];
    const float* WB = (const float*)d_in[1];
    const float* BA = (const float*)d_in[2];
    const float* W  = (const float*)d_in[3];
    const float* D  = (const float*)d_in[4];
    float* Y = (float*)d_out;

    char* ws = (char*)d_ws;
    float*          XH = (float*)ws;
    unsigned short* Wk = (unsigned short*)(ws + (1u << 20));
    unsigned short* YH = (unsigned short*)(ws + (1u << 20) + (size_t)CIN * COUT * MODES * 2);

    hipMemsetAsync(XH, 0, (size_t)B_ * CIN * MODES * sizeof(float), stream);

    k1_wk  <<<256,            256, 0, stream>>>(W, D, Wk);
    k2_xhat<<<dim3(32, 2, 8), 256, 0, stream>>>(X, WB, XH);
    k3_yhat<<<dim3(32, 8),    256, 0, stream>>>(XH, Wk, YH);
    k4_y   <<<dim3(64, 8),    256, 0, stream>>>(YH, BA, Y);
}

// Round 5
// 220.279 us; speedup vs baseline: 1.1412x; 1.1400x over previous
//
#include <hip/hip_runtime.h>

#define B_    8
#define CIN   128
#define COUT  128
#define NX    8192
#define KMJ   32
#define MODES 256

typedef short bf16x8 __attribute__((ext_vector_type(8)));
typedef float f32x4  __attribute__((ext_vector_type(4)));

__device__ __forceinline__ float bf2f(unsigned short u) {
    union { unsigned int i; float f; } v; v.i = ((unsigned int)u) << 16; return v.f;
}
__device__ __forceinline__ unsigned short f2bf(float f) {
    union { float f; unsigned int i; } v; v.f = f;
    unsigned int x = v.i;
    return (unsigned short)((x + 0x7fffu + ((x >> 16) & 1u)) >> 16);
}
__device__ __forceinline__ bf16x8 cvt8(const float* __restrict__ p) {
    f32x4 a = *(const f32x4*)p;
    f32x4 b = *(const f32x4*)(p + 4);
    bf16x8 r;
    r[0] = (short)f2bf(a[0]); r[1] = (short)f2bf(a[1]);
    r[2] = (short)f2bf(a[2]); r[3] = (short)f2bf(a[3]);
    r[4] = (short)f2bf(b[0]); r[5] = (short)f2bf(b[1]);
    r[6] = (short)f2bf(b[2]); r[7] = (short)f2bf(b[3]);
    return r;
}
__device__ __forceinline__ ushort4 cvt4(f32x4 a) {
    ushort4 r;
    r.x = f2bf(a[0]); r.y = f2bf(a[1]); r.z = f2bf(a[2]); r.w = f2bf(a[3]);
    return r;
}

// ---------------------------------------------------------------------------
// K1 v2: Wk[k][o][i] = sum_j D[j][k] * weights[i][o][j]
// MFMA with A = D^T (M = k), B = weights viewed as [j][(o,i)] (N = o*128+i).
// Output comes out in [k][o*128+i] with coalesced stores.
// ---------------------------------------------------------------------------
__global__ __launch_bounds__(256) void k1_wk(const float* __restrict__ W,
                                             const float* __restrict__ D,
                                             unsigned short* __restrict__ Wk) {
    int wave = threadIdx.x >> 6, lane = threadIdx.x & 63;
    int quad = lane >> 4, l16 = lane & 15;
    int gw  = blockIdx.x * 4 + wave;    // 0..1023 : n-tile of 16 over oi = o*128+i
    int oi0 = gw * 16;
    int i0  = oi0 & 127, o0 = oi0 >> 7; // oi0 16-aligned -> tile has fixed o
    // B[j = quad*8+jj][n = oi0+l16] = weights[(i0+l16)*128 + o0][j]
    bf16x8 bfrag = cvt8(W + ((size_t)(i0 + l16) * COUT + o0) * KMJ + quad * 8);
    for (int mt = 0; mt < 16; mt++) {
        int k0 = mt * 16;
        // A[m = l16][kdim = quad*8+jj] = D[j][k0+l16]
        bf16x8 afrag;
#pragma unroll
        for (int jj = 0; jj < 8; jj++)
            afrag[jj] = (short)f2bf(D[(quad * 8 + jj) * MODES + k0 + l16]);
        f32x4 acc = {0.f, 0.f, 0.f, 0.f};
        acc = __builtin_amdgcn_mfma_f32_16x16x32_bf16(afrag, bfrag, acc, 0, 0, 0);
        // C/D: col(n=oi) = l16, row(m=k) = quad*4+r -> coalesced 16x2B stores
#pragma unroll
        for (int r = 0; r < 4; r++)
            Wk[(size_t)(k0 + quad * 4 + r) * (CIN * COUT) + oi0 + l16] = f2bf(acc[r]);
    }
}

// ---------------------------------------------------------------------------
// K2 v3: PART[b][nt][c][k] = sum_{n in nt-chunk} x[b][c][n]*wb[b][n][k]  (bf16)
// NO ATOMICS (round-4 counters: 8.4M atomicAdds were the 65us bottleneck —
// two different k2 structures timed identically; WRITE_SIZE == natomics*4B).
// grid (32 nt, 8 b) = 256 blocks, 512 thr (8 waves, 2m x 4n of 64x64 tiles).
// Coalesced f32x4 staging -> bf16 LDS; 8 K-steps of 32 n; bf16 partial out.
// ---------------------------------------------------------------------------
__global__ __launch_bounds__(512) void k2_xhat(const float* __restrict__ X,
                                               const float* __restrict__ WB,
                                               unsigned short* __restrict__ PART) {
    __shared__ __align__(16) unsigned short Xs[128 * 40];    // [c][40], cols 0..31
    __shared__ __align__(16) unsigned short WBs[32 * 260];   // [n][260], cols 0..255
    int nt = blockIdx.x, b = blockIdx.y;
    int r0 = nt * 256;
    int t  = threadIdx.x;
    int wave = t >> 6, lane = t & 63;
    int wm = wave >> 2, wn = wave & 3;
    int quad = lane >> 4, l16 = lane & 15;

    const float* xb  = X  + (size_t)b * CIN * NX;
    const float* wbb = WB + (size_t)b * NX * MODES;

    int xn4 = t & 7,  xc  = t >> 3;   // X: 8 f32x4 per 32-n row; rows xc, xc+64
    int wk4 = t & 63, wn0 = t >> 6;   // WB: 64 f32x4 per 256-k row; rows wn0+8r

    f32x4 acc[4][4];
#pragma unroll
    for (int i = 0; i < 4; i++)
#pragma unroll
        for (int j = 0; j < 4; j++) acc[i][j] = (f32x4){0.f, 0.f, 0.f, 0.f};

    for (int s = 0; s < 8; s++) {
        int rs = r0 + s * 32;
        f32x4 xv0 = *(const f32x4*)(xb + (size_t)xc * NX + rs + xn4 * 4);
        f32x4 xv1 = *(const f32x4*)(xb + (size_t)(xc + 64) * NX + rs + xn4 * 4);
        f32x4 wv[4];
#pragma unroll
        for (int r = 0; r < 4; r++)
            wv[r] = *(const f32x4*)(wbb + (size_t)(rs + wn0 + 8 * r) * MODES + wk4 * 4);

        __syncthreads();   // previous step's frag reads complete
        *(ushort4*)(Xs + xc * 40 + xn4 * 4)        = cvt4(xv0);
        *(ushort4*)(Xs + (xc + 64) * 40 + xn4 * 4) = cvt4(xv1);
#pragma unroll
        for (int r = 0; r < 4; r++)
            *(ushort4*)(WBs + (wn0 + 8 * r) * 260 + wk4 * 4) = cvt4(wv[r]);
        __syncthreads();   // staging visible

        bf16x8 af[4];
#pragma unroll
        for (int tm = 0; tm < 4; tm++)
            af[tm] = *(const bf16x8*)(Xs + (wm * 64 + tm * 16 + l16) * 40 + quad * 8);
        bf16x8 bfv[4];
#pragma unroll
        for (int tn = 0; tn < 4; tn++) {
            int km = wn * 64 + tn * 16 + l16;
#pragma unroll
            for (int jj = 0; jj < 8; jj++)
                bfv[tn][jj] = (short)WBs[(quad * 8 + jj) * 260 + km];
        }
#pragma unroll
        for (int tm = 0; tm < 4; tm++)
#pragma unroll
            for (int tn = 0; tn < 4; tn++)
                acc[tm][tn] = __builtin_amdgcn_mfma_f32_16x16x32_bf16(af[tm], bfv[tn], acc[tm][tn], 0, 0, 0);
    }

    unsigned short* pb = PART + ((size_t)b * 32 + nt) * (CIN * MODES);
#pragma unroll
    for (int tm = 0; tm < 4; tm++) {
        int c = wm * 64 + tm * 16 + quad * 4;
#pragma unroll
        for (int tn = 0; tn < 4; tn++) {
            int km = wn * 64 + tn * 16 + l16;
#pragma unroll
            for (int r = 0; r < 4; r++)
                pb[(size_t)(c + r) * MODES + km] = f2bf(acc[tm][tn][r]);
        }
    }
}

// ---------------------------------------------------------------------------
// K2b: XH[b][c][k] = sum_nt PART[b][nt][c][k]   (fp32 out, coalesced)
// ---------------------------------------------------------------------------
__global__ __launch_bounds__(256) void k2b_red(const unsigned short* __restrict__ PART,
                                               float* __restrict__ XH) {
    int e0 = blockIdx.x * 1024 + threadIdx.x;
#pragma unroll
    for (int r = 0; r < 4; r++) {
        int e = e0 + r * 256;                  // 0..262143
        int b = e >> 15, rem = e & 32767;
        const unsigned short* p = PART + (size_t)b * 32 * (CIN * MODES) + rem;
        float acc = 0.f;
#pragma unroll
        for (int nt = 0; nt < 32; nt++) acc += bf2f(p[nt * (CIN * MODES)]);
        XH[e] = acc;
    }
}

// ---------------------------------------------------------------------------
// K3 v2: y_hat[b][o][k] = sum_i x_hat[b][i][k] * Wk[k][o][i]
// One block per mode k. Wk rows contiguous in i -> bf16x8 loads; x-slice in
// LDS as [i][b], read as broadcast f32x4 (all lanes same address = free).
// ---------------------------------------------------------------------------
__global__ __launch_bounds__(256) void k3_yhat(const float* __restrict__ XH,
                                               const unsigned short* __restrict__ Wk,
                                               unsigned short* __restrict__ YH) {
    __shared__ float xs[128][8];
    int k = blockIdx.x;
    int t = threadIdx.x;
#pragma unroll
    for (int l = 0; l < 4; l++) {
        int e = l * 256 + t;                   // 0..1023
        int i = e >> 3, b = e & 7;
        xs[i][b] = XH[(size_t)b * (CIN * MODES) + (size_t)i * MODES + k];
    }
    __syncthreads();
    int o = t & 127, bh = t >> 7;              // bh: b-half (4 b's each)
    const unsigned short* wp = Wk + (size_t)k * (CIN * COUT) + (size_t)o * CIN;
    f32x4 acc = {0.f, 0.f, 0.f, 0.f};
    for (int ii = 0; ii < 16; ii++) {
        bf16x8 wc = *(const bf16x8*)(wp + ii * 8);
#pragma unroll
        for (int jj = 0; jj < 8; jj++) {
            float w = bf2f((unsigned short)wc[jj]);
            f32x4 xv = *(const f32x4*)&xs[ii * 8 + jj][bh * 4];
            acc += w * xv;
        }
    }
#pragma unroll
    for (int r = 0; r < 4; r++)
        YH[((size_t)(bh * 4 + r) * COUT + o) * MODES + k] = f2bf(acc[r]);
}

// ---------------------------------------------------------------------------
// K4 v2: y[b][c][n] = sum_k y_hat[b][c][k] * bases[b][n][k]
// NT GEMM, 128x128 tile, 4 waves. Register prefetch of step s+1 issued
// before MFMA(s); the pre-barrier vmcnt(0) drain of the next iteration then
// lands after ~16 MFMA of overlap.
// ---------------------------------------------------------------------------
__global__ __launch_bounds__(256) void k4_y(const unsigned short* __restrict__ YH,
                                            const float* __restrict__ BA,
                                            float* __restrict__ Y) {
    __shared__ __align__(16) unsigned short As[128 * 32];
    __shared__ __align__(16) unsigned short Bs[128 * 32];
    int b  = blockIdx.y;
    int n0 = blockIdx.x * 128;
    int t  = threadIdx.x;
    int wave = t >> 6, lane = t & 63;
    int wm = wave >> 1, wn = wave & 1;
    int quad = lane >> 4, l16 = lane & 15;

    const unsigned short* yhb = YH + (size_t)b * COUT * MODES;
    const float* bab = BA + (size_t)b * NX * MODES + (size_t)n0 * MODES;

    int E0 = t * 8;              // chunk p: element E = p*2048 + E0
    int row0 = E0 >> 5, kk0 = E0 & 31;
    int row1 = (2048 + E0) >> 5, kk1 = (2048 + E0) & 31;

    f32x4 acc[4][4];
#pragma unroll
    for (int i = 0; i < 4; i++)
#pragma unroll
        for (int j = 0; j < 4; j++) acc[i][j] = (f32x4){0.f, 0.f, 0.f, 0.f};

    // preload step 0
    bf16x8 av0 = *(const bf16x8*)(yhb + (size_t)row0 * MODES + kk0);
    bf16x8 av1 = *(const bf16x8*)(yhb + (size_t)row1 * MODES + kk1);
    f32x4 bv0a = *(const f32x4*)(bab + (size_t)row0 * MODES + kk0);
    f32x4 bv0b = *(const f32x4*)(bab + (size_t)row0 * MODES + kk0 + 4);
    f32x4 bv1a = *(const f32x4*)(bab + (size_t)row1 * MODES + kk1);
    f32x4 bv1b = *(const f32x4*)(bab + (size_t)row1 * MODES + kk1 + 4);

    for (int step = 0; step < 8; step++) {
        __syncthreads();   // previous step's frag reads complete (no-op at s=0)
        *(bf16x8*)(As + E0)        = av0;
        *(bf16x8*)(As + 2048 + E0) = av1;
        bf16x8 bs0, bs1;
        bs0[0]=(short)f2bf(bv0a[0]); bs0[1]=(short)f2bf(bv0a[1]);
        bs0[2]=(short)f2bf(bv0a[2]); bs0[3]=(short)f2bf(bv0a[3]);
        bs0[4]=(short)f2bf(bv0b[0]); bs0[5]=(short)f2bf(bv0b[1]);
        bs0[6]=(short)f2bf(bv0b[2]); bs0[7]=(short)f2bf(bv0b[3]);
        bs1[0]=(short)f2bf(bv1a[0]); bs1[1]=(short)f2bf(bv1a[1]);
        bs1[2]=(short)f2bf(bv1a[2]); bs1[3]=(short)f2bf(bv1a[3]);
        bs1[4]=(short)f2bf(bv1b[0]); bs1[5]=(short)f2bf(bv1b[1]);
        bs1[6]=(short)f2bf(bv1b[2]); bs1[7]=(short)f2bf(bv1b[3]);
        *(bf16x8*)(Bs + E0)        = bs0;
        *(bf16x8*)(Bs + 2048 + E0) = bs1;
        __syncthreads();   // staging visible

        if (step < 7) {    // prefetch s+1 into regs; drains during MFMA below
            int ks = (step + 1) * 32;
            av0  = *(const bf16x8*)(yhb + (size_t)row0 * MODES + ks + kk0);
            av1  = *(const bf16x8*)(yhb + (size_t)row1 * MODES + ks + kk1);
            bv0a = *(const f32x4*)(bab + (size_t)row0 * MODES + ks + kk0);
            bv0b = *(const f32x4*)(bab + (size_t)row0 * MODES + ks + kk0 + 4);
            bv1a = *(const f32x4*)(bab + (size_t)row1 * MODES + ks + kk1);
            bv1b = *(const f32x4*)(bab + (size_t)row1 * MODES + ks + kk1 + 4);
        }

        bf16x8 af[4], bfv[4];
#pragma unroll
        for (int tm = 0; tm < 4; tm++) {
            int c = wm * 64 + tm * 16 + l16;
            af[tm] = *(const bf16x8*)(As + c * 32 + quad * 8);
        }
#pragma unroll
        for (int tn = 0; tn < 4; tn++) {
            int n = wn * 64 + tn * 16 + l16;
            bfv[tn] = *(const bf16x8*)(Bs + n * 32 + quad * 8);
        }
#pragma unroll
        for (int tm = 0; tm < 4; tm++)
#pragma unroll
            for (int tn = 0; tn < 4; tn++)
                acc[tm][tn] = __builtin_amdgcn_mfma_f32_16x16x32_bf16(af[tm], bfv[tn], acc[tm][tn], 0, 0, 0);
    }

    float* yb = Y + (size_t)b * COUT * NX;
#pragma unroll
    for (int tm = 0; tm < 4; tm++) {
        int o = wm * 64 + tm * 16 + quad * 4;
#pragma unroll
        for (int tn = 0; tn < 4; tn++) {
            int n = n0 + wn * 64 + tn * 16 + l16;
#pragma unroll
            for (int r = 0; r < 4; r++)
                yb[(size_t)(o + r) * NX + n] = acc[tm][tn][r];
        }
    }
}

extern "C" void kernel_launch(void* const* d_in, const int* in_sizes, int n_in,
                              void* d_out, int out_size, void* d_ws, size_t ws_size,
                              hipStream_t stream) {
    const float* X  = (const float*)d_in[0];  // [8][128][8192]
    const float* WB = (const float*)d_in[1];  // [8][8192][256]
    const float* BA = (const float*)d_in[2];  // [8][8192][256]
    const float* W  = (const float*)d_in[3];  // [128][128][32]
    const float* D  = (const float*)d_in[4];  // [32][256]
    float* Y = (float*)d_out;                 // [8][128][8192]

    char* ws = (char*)d_ws;
    unsigned short* Wk   = (unsigned short*)ws;                  // 8 MB bf16 [k][o][i]
    float*          XH   = (float*)(ws + (8u << 20));            // 1 MB fp32 [b][c][k]
    unsigned short* YH   = (unsigned short*)(ws + (9u << 20));   // 0.5 MB bf16 [b][o][k]
    unsigned short* PART = (unsigned short*)(ws + (10u << 20));  // 16.75 MB bf16 [b][nt][c][k]

    k1_wk  <<<256,          256, 0, stream>>>(W, D, Wk);
    k2_xhat<<<dim3(32, 8),  512, 0, stream>>>(X, WB, PART);
    k2b_red<<<256,          256, 0, stream>>>(PART, XH);
    k3_yhat<<<MODES,        256, 0, stream>>>(XH, Wk, YH);
    k4_y   <<<dim3(64, 8),  256, 0, stream>>>(YH, BA, Y);
}